// Round 3
// baseline (422.560 us; speedup 1.0000x reference)
//
#include <hip/hip_runtime.h>

// out[M,N] = (int8 a[M,K] @ int8 w[K,N]) * a_scale[M] * w_scale[N]
// M = 8192, K = 4096, N = 4096. Inputs arrive as int32 containers.
//
// Structure: pack int32->int8 into d_ws in MFMA-fragment-ordered 256x64 tiles
// (layout makes LDS reads conflict-free and global_load_lds linear), then a
// 256x256-tile 8-wave GEMM in the m201 8-phase style: 2 phases per K-tile,
// counted vmcnt(2) (never 0 in the main loop), two barriers per phase,
// setprio(1) around the MFMA cluster, XCD-aware block swizzle.

#define M_TOT 8192
#define N_TOT 4096
#define K_TOT 4096
#define NT_K  (K_TOT / 64)     // 64 K-tiles of depth 64
#define TILE_BYTES 16384       // 256 rows x 64 k x 1 B

typedef int v4i  __attribute__((ext_vector_type(4)));
typedef int v16i __attribute__((ext_vector_type(16)));

typedef const __attribute__((address_space(1))) unsigned char* gas1_t;
typedef __attribute__((address_space(3))) unsigned char* las3_t;

// ---------------------------------------------------------------------------
// Pack A: a[M][K] int32 -> a8 tiles [mt(32)][kt(64)][slot(4)][m(256)][16B]
//   byte (slot*4096 + m*16 + j) = (int8) a[mt*256+m][kt*64 + slot*16 + j]
// Thread t handles row m=t: reads 4x64B (row-contiguous), writes 4x16B.
// ---------------------------------------------------------------------------
__global__ __launch_bounds__(256) void pack_a_kernel(const int* __restrict__ a,
                                                     unsigned char* __restrict__ a8) {
    const int tile = blockIdx.x;            // mt*NT_K + kt
    const int kt = tile & (NT_K - 1);
    const int mt = tile >> 6;
    const int t = threadIdx.x;              // row within tile
    unsigned char* outp = a8 + (size_t)tile * TILE_BYTES;
    const int* rowp = a + (size_t)(mt * 256 + t) * K_TOT + kt * 64;
#pragma unroll
    for (int slot = 0; slot < 4; ++slot) {
        const int* src = rowp + slot * 16;
        int4 v0 = ((const int4*)src)[0];
        int4 v1 = ((const int4*)src)[1];
        int4 v2 = ((const int4*)src)[2];
        int4 v3 = ((const int4*)src)[3];
        int4 p;
        p.x = (int)((unsigned)(v0.x & 255) | ((unsigned)(v0.y & 255) << 8) |
                    ((unsigned)(v0.z & 255) << 16) | ((unsigned)v0.w << 24));
        p.y = (int)((unsigned)(v1.x & 255) | ((unsigned)(v1.y & 255) << 8) |
                    ((unsigned)(v1.z & 255) << 16) | ((unsigned)v1.w << 24));
        p.z = (int)((unsigned)(v2.x & 255) | ((unsigned)(v2.y & 255) << 8) |
                    ((unsigned)(v2.z & 255) << 16) | ((unsigned)v2.w << 24));
        p.w = (int)((unsigned)(v3.x & 255) | ((unsigned)(v3.y & 255) << 8) |
                    ((unsigned)(v3.z & 255) << 16) | ((unsigned)v3.w << 24));
        *(int4*)(outp + slot * 4096 + t * 16) = p;
    }
}

// ---------------------------------------------------------------------------
// Pack W (transpose): w[K][N] int32 -> w8 tiles [nt(16)][kt(64)][slot(4)][n(256)][16B]
//   byte (slot*4096 + n*16 + j) = (int8) w[kt*64 + slot*16 + j][nt*256 + n]
// Thread t handles col n=t: 16 row-strided loads per slot, coalesced across lanes.
// ---------------------------------------------------------------------------
__global__ __launch_bounds__(256) void pack_w_kernel(const int* __restrict__ w,
                                                     unsigned char* __restrict__ w8) {
    const int tile = blockIdx.x;            // nt*NT_K + kt
    const int kt = tile & (NT_K - 1);
    const int nt = tile >> 6;
    const int t = threadIdx.x;              // col within tile
    unsigned char* outp = w8 + (size_t)tile * TILE_BYTES;
#pragma unroll
    for (int slot = 0; slot < 4; ++slot) {
        const int* src = w + (size_t)(kt * 64 + slot * 16) * N_TOT + nt * 256 + t;
        int b[16];
#pragma unroll
        for (int j = 0; j < 16; ++j) b[j] = src[(size_t)j * N_TOT];
        int4 p;
        p.x = (int)((unsigned)(b[0] & 255) | ((unsigned)(b[1] & 255) << 8) |
                    ((unsigned)(b[2] & 255) << 16) | ((unsigned)b[3] << 24));
        p.y = (int)((unsigned)(b[4] & 255) | ((unsigned)(b[5] & 255) << 8) |
                    ((unsigned)(b[6] & 255) << 16) | ((unsigned)b[7] << 24));
        p.z = (int)((unsigned)(b[8] & 255) | ((unsigned)(b[9] & 255) << 8) |
                    ((unsigned)(b[10] & 255) << 16) | ((unsigned)b[11] << 24));
        p.w = (int)((unsigned)(b[12] & 255) | ((unsigned)(b[13] & 255) << 8) |
                    ((unsigned)(b[14] & 255) << 16) | ((unsigned)b[15] << 24));
        *(int4*)(outp + slot * 4096 + t * 16) = p;
    }
}

// ---------------------------------------------------------------------------
// GEMM: 256x256 tile, BK=64, 8 waves (2M x 4N; 128x64 out per wave),
// mfma_i32_32x32x32_i8, dbuf LDS (2 x 32 KB), 2 phases per K-tile.
//
// A-frag: lane l holds A[row = l&31][k = kc*32 + (l>>5)*16 + j], j=0..15
// B-frag: lane l holds B[k][col = l&31]  (same k mapping; any consistent
//         k-permutation cancels in the dot product)
// D:      lane l, reg r -> row = (r&3) + 8*(r>>2) + 4*(l>>5), col = l&31
//         (m74/m101 HW-verified; dtype-independent m121-128)
//
// Phase schedule (m201 template): {6 ds_read_b128; 2 global_load_lds prefetch;
// vmcnt(2); barrier; lgkmcnt(0); sched_barrier; setprio(1); 8 MFMA; setprio(0);
// barrier}. Chunk = 8 KB = one 512-thread gload_lds issue. Prefetch distance =
// 1 K-tile (4 chunks in flight max); vmcnt(2) guarantees the 2-phase-old chunk
// pair has landed before the next phase's ds_reads (issue order A,B per phase).
// ---------------------------------------------------------------------------
__global__ __launch_bounds__(512, 2) void gemm_i8_kernel(
    const unsigned char* __restrict__ a8, const unsigned char* __restrict__ w8,
    const float* __restrict__ a_scale, const float* __restrict__ w_scale,
    float* __restrict__ out) {

    __shared__ __attribute__((aligned(16))) unsigned char sm[2][2][TILE_BYTES]; // 64 KB

    const int t = threadIdx.x;
    const int lane = t & 63;
    const int wid = t >> 6;           // 0..7
    const int wr = wid >> 2;          // 0..1 : rows [wr*128, +128)
    const int wc = wid & 3;           // 0..3 : cols [wc*64, +64)
    const int hi = lane >> 5;         // k-half within 32-k chunk
    const int lo32 = lane & 31;

    // XCD-aware swizzle: grid 512, 512 % 8 == 0 -> bijective chunked map
    int bid = blockIdx.x;
    bid = (bid & 7) * (512 / 8) + (bid >> 3);
    const int mt = bid >> 4;          // 0..31  (N_TOT/256 = 16 tiles per row)
    const int nt = bid & 15;

    const unsigned char* a_tiles = a8 + (size_t)mt * NT_K * TILE_BYTES;
    const unsigned char* w_tiles = w8 + (size_t)nt * NT_K * TILE_BYTES;

    v16i acc[4][2] = {};

#define STAGE_CHUNK(pbuf, op, half, gsrc)                                         \
    __builtin_amdgcn_global_load_lds((gas1_t)((gsrc) + (half) * 8192 + t * 16),   \
        (las3_t)&sm[pbuf][op][(half) * 8192 + t * 16], 16, 0, 0)

#define PHASE(buf, kc, gaN, gbN) do {                                             \
    const unsigned char* lA = &sm[buf][0][0];                                     \
    const unsigned char* lB = &sm[buf][1][0];                                     \
    const int so = ((kc) * 2 + hi) * 4096;                                        \
    v4i af[4], bf[2];                                                             \
    _Pragma("unroll")                                                             \
    for (int mi = 0; mi < 4; ++mi)                                                \
        af[mi] = *(const v4i*)(lA + so + (wr * 128 + mi * 32 + lo32) * 16);       \
    _Pragma("unroll")                                                             \
    for (int ni = 0; ni < 2; ++ni)                                                \
        bf[ni] = *(const v4i*)(lB + so + (wc * 64 + ni * 32 + lo32) * 16);        \
    STAGE_CHUNK((buf) ^ 1, 0, (kc), gaN);                                         \
    STAGE_CHUNK((buf) ^ 1, 1, (kc), gbN);                                         \
    asm volatile("s_waitcnt vmcnt(2)" ::: "memory");                              \
    __builtin_amdgcn_s_barrier();                                                 \
    asm volatile("s_waitcnt lgkmcnt(0)" ::: "memory");                            \
    __builtin_amdgcn_sched_barrier(0);                                            \
    __builtin_amdgcn_s_setprio(1);                                                \
    _Pragma("unroll")                                                             \
    for (int mi = 0; mi < 4; ++mi)                                                \
        _Pragma("unroll")                                                         \
        for (int ni = 0; ni < 2; ++ni)                                            \
            acc[mi][ni] = __builtin_amdgcn_mfma_i32_32x32x32_i8(                  \
                af[mi], bf[ni], acc[mi][ni], 0, 0, 0);                            \
    __builtin_amdgcn_s_setprio(0);                                                \
    __builtin_amdgcn_s_barrier();                                                 \
} while (0)

    // Prologue: stage tile 0 (issue order A-lo, B-lo, A-hi, B-hi), then the
    // uniform counted wait: vmcnt(2) -> A-lo,B-lo landed for the first phase.
    STAGE_CHUNK(0, 0, 0, a_tiles);
    STAGE_CHUNK(0, 1, 0, w_tiles);
    STAGE_CHUNK(0, 0, 1, a_tiles);
    STAGE_CHUNK(0, 1, 1, w_tiles);
    asm volatile("s_waitcnt vmcnt(2)" ::: "memory");
    __builtin_amdgcn_s_barrier();

    // Main loop: tile T in buf[T&1]; its phases prefetch tile T+1 into buf^1.
    // Last-iteration prefetches clamp to tile NT_K-1 (redundant, dead, safe).
#pragma unroll 1
    for (int T = 0; T < NT_K; T += 2) {
        const int Tn1 = (T + 1 < NT_K) ? T + 1 : NT_K - 1;
        const int Tn2 = (T + 2 < NT_K) ? T + 2 : NT_K - 1;
        const unsigned char* ga1 = a_tiles + (size_t)Tn1 * TILE_BYTES;
        const unsigned char* gb1 = w_tiles + (size_t)Tn1 * TILE_BYTES;
        const unsigned char* ga2 = a_tiles + (size_t)Tn2 * TILE_BYTES;
        const unsigned char* gb2 = w_tiles + (size_t)Tn2 * TILE_BYTES;
        PHASE(0, 0, ga1, gb1);
        PHASE(0, 1, ga1, gb1);
        PHASE(1, 0, ga2, gb2);
        PHASE(1, 1, ga2, gb2);
    }

    // Drain outstanding gload_lds before LDS dealloc / exit.
    asm volatile("s_waitcnt vmcnt(0)" ::: "memory");

#undef STAGE_CHUNK
#undef PHASE

    // Epilogue: dequant + store f32.
    const int row0 = mt * 256 + wr * 128;
    const int col0 = nt * 256 + wc * 64;
#pragma unroll
    for (int mi = 0; mi < 4; ++mi) {
#pragma unroll
        for (int r = 0; r < 16; ++r) {
            const int row = row0 + mi * 32 + (r & 3) + 8 * (r >> 2) + 4 * hi;
            const float as = a_scale[row];
            float* orow = out + (size_t)row * N_TOT + col0 + lo32;
#pragma unroll
            for (int ni = 0; ni < 2; ++ni)
                orow[ni * 32] = (float)acc[mi][ni][r] * as * w_scale[col0 + ni * 32 + lo32];
        }
    }
}

// ---------------------------------------------------------------------------
extern "C" void kernel_launch(void* const* d_in, const int* in_sizes, int n_in,
                              void* d_out, int out_size, void* d_ws, size_t ws_size,
                              hipStream_t stream) {
    const int*   a       = (const int*)d_in[0];
    const float* a_scale = (const float*)d_in[1];
    const int*   w       = (const int*)d_in[2];
    const float* w_scale = (const float*)d_in[3];
    float*       out     = (float*)d_out;

    // Workspace: a8 (32 MB) + w8 (16 MB) = 48 MB
    unsigned char* a8 = (unsigned char*)d_ws;
    unsigned char* w8 = a8 + (size_t)M_TOT * K_TOT;

    pack_a_kernel<<<(M_TOT / 256) * NT_K, 256, 0, stream>>>(a, a8);   // 2048 blocks
    pack_w_kernel<<<(N_TOT / 256) * NT_K, 256, 0, stream>>>(w, w8);   // 1024 blocks
    gemm_i8_kernel<<<(M_TOT / 256) * (N_TOT / 256), 512, 0, stream>>>(
        a8, w8, a_scale, w_scale, out);                               // 512 blocks
}

// Round 4
// 402.279 us; speedup vs baseline: 1.0504x; 1.0504x over previous
//
#include <hip/hip_runtime.h>

// out[M,N] = (int8 a[M,K] @ int8 w[K,N]) * a_scale[M] * w_scale[N]
// M = 8192, K = 4096, N = 4096. Inputs arrive as int32 containers.
//
// R3 measured: total 422 us; GEMM 152 us (MfmaUtil 42%, bank-conflict 0);
// packs ~270 us (pack_a reads uncoalesced, 16KB lane stride). R4 changes:
// (1) both packs restructured to coalesced-read -> LDS transpose -> coalesced
//     write; (2) GEMM: one phase per K-tile, triple-buffered LDS, counted
//     vmcnt(4) never drained in-loop, 2 barriers + 16-MFMA cluster per K-tile.

#define M_TOT 8192
#define N_TOT 4096
#define K_TOT 4096
#define NT_K  (K_TOT / 64)     // 64 K-tiles of depth 64
#define TILE_BYTES 16384       // 256 rows x 64 k x 1 B

typedef int v4i  __attribute__((ext_vector_type(4)));
typedef int v16i __attribute__((ext_vector_type(16)));

typedef const __attribute__((address_space(1))) unsigned char* gas1_t;
typedef __attribute__((address_space(3))) unsigned char* las3_t;

__device__ __forceinline__ int pack4(int4 v) {
    return (int)((unsigned)(v.x & 255) | ((unsigned)(v.y & 255) << 8) |
                 ((unsigned)(v.z & 255) << 16) | ((unsigned)v.w << 24));
}

// ---------------------------------------------------------------------------
// Pack A: a[M][K] int32 -> a8 tiles [mt(32)][kt(64)][slot(4)][m(256)][16B]
//   byte (slot*4096 + m*16 + j) = (int8) a[mt*256+m][kt*64 + slot*16 + j]
// Phase 1: coalesced int4 reads (16 lanes cover one row's 256 B) -> LDS,
//   XOR-swizzled 16B chunks (without swizzle, phase 2 is a same-bank
//   64-lane read: addr16 = t*16 + const -> single bank).
// Phase 2: per slot, gather 4 swizzled chunks of own row, pack, store
//   coalesced (consecutive t -> consecutive 16 B).
// ---------------------------------------------------------------------------
__global__ __launch_bounds__(256) void pack_a_kernel(const int* __restrict__ a,
                                                     unsigned char* __restrict__ a8) {
    __shared__ int4 stage[256 * 16];        // 64 KB, addr16 = r*16 + (c ^ (r&15))
    const int tile = blockIdx.x;            // mt*NT_K + kt
    const int kt = tile & (NT_K - 1);
    const int mt = tile >> 6;
    const int t = threadIdx.x;
#pragma unroll
    for (int i = 0; i < 16; ++i) {
        const int idx16 = i * 256 + t;
        const int r = idx16 >> 4;           // row 0..255
        const int c = idx16 & 15;           // 16B chunk within row
        int4 v = *(const int4*)(a + (size_t)(mt * 256 + r) * K_TOT + kt * 64 + c * 4);
        stage[r * 16 + (c ^ (r & 15))] = v;
    }
    __syncthreads();
    unsigned char* outp = a8 + (size_t)tile * TILE_BYTES;
#pragma unroll
    for (int j = 0; j < 4; ++j) {           // slot = k-group of 16
        int4 d0 = stage[t * 16 + ((j * 4 + 0) ^ (t & 15))];
        int4 d1 = stage[t * 16 + ((j * 4 + 1) ^ (t & 15))];
        int4 d2 = stage[t * 16 + ((j * 4 + 2) ^ (t & 15))];
        int4 d3 = stage[t * 16 + ((j * 4 + 3) ^ (t & 15))];
        int4 p = { pack4(d0), pack4(d1), pack4(d2), pack4(d3) };
        *(int4*)(outp + j * 4096 + t * 16) = p;
    }
}

// ---------------------------------------------------------------------------
// Pack W (transpose): w[K][N] int32 -> w8 tiles [nt(16)][kt(64)][slot(4)][n(256)][16B]
//   byte (slot*4096 + n*16 + j) = (int8) w[kt*64 + slot*16 + j][nt*256 + n]
// Phase 1: coalesced int4 reads (wave covers 1 KB of one k-row) -> LDS [k][n].
// Phase 2: thread t = col n; 16 stride-256 dword reads (bank = t%32, 2-way
//   alias across lane halves = free), pack, coalesced 16B store.
// ---------------------------------------------------------------------------
__global__ __launch_bounds__(256) void pack_w_kernel(const int* __restrict__ w,
                                                     unsigned char* __restrict__ w8) {
    __shared__ int stage[64 * 256];         // 64 KB, [k][n] dwords
    const int tile = blockIdx.x;            // nt*NT_K + kt
    const int kt = tile & (NT_K - 1);
    const int nt = tile >> 6;
    const int t = threadIdx.x;
#pragma unroll
    for (int i = 0; i < 16; ++i) {
        const int idx = i * 256 + t;
        const int k = idx >> 6;             // k-row 0..63
        const int c4 = idx & 63;            // int4 chunk within row (64 per row)
        int4 v = *(const int4*)(w + (size_t)(kt * 64 + k) * N_TOT + nt * 256 + c4 * 4);
        *(int4*)&stage[k * 256 + c4 * 4] = v;
    }
    __syncthreads();
    unsigned char* outp = w8 + (size_t)tile * TILE_BYTES;
#pragma unroll
    for (int j = 0; j < 4; ++j) {           // slot
        int4 p;
#pragma unroll
        for (int qq = 0; qq < 4; ++qq) {
            int4 b;
            b.x = stage[(j * 16 + qq * 4 + 0) * 256 + t];
            b.y = stage[(j * 16 + qq * 4 + 1) * 256 + t];
            b.z = stage[(j * 16 + qq * 4 + 2) * 256 + t];
            b.w = stage[(j * 16 + qq * 4 + 3) * 256 + t];
            ((int*)&p)[qq] = pack4(b);
        }
        *(int4*)(outp + j * 4096 + t * 16) = p;
    }
}

// ---------------------------------------------------------------------------
// GEMM: 256x256 tile, BK=64, 8 waves (2M x 4N; 128x64 out per wave),
// mfma_i32_32x32x32_i8, TRIPLE-buffered LDS (96 KB), 1 phase per K-tile:
//   { stage tile T+2 -> buf (T+2)%3 (4 x global_load_lds, 16B);
//     12 x ds_read_b128 of tile T from buf T%3;
//     vmcnt(4)  [allows the 4 just-issued; guarantees tile T+1 landed];
//     barrier; lgkmcnt(0); sched_barrier; setprio(1); 16 MFMA; setprio(0);
//     barrier  [protects buf T%3, overwritten by iter T+1's stage] }
// vmcnt is never 0 inside the loop (T4). Loop unrolled x3 so the buffer
// indices constant-fold (64 iters = 21*3 + 1).
//
// A-frag: lane l holds A[row = l&31][k = kc*32 + (l>>5)*16 + j], j=0..15
// B-frag: lane l holds B[k][col = l&31] (same k map; consistent permutation
//         cancels in the dot product)
// D: lane l, reg r -> row = (r&3) + 8*(r>>2) + 4*(l>>5), col = l&31
// ---------------------------------------------------------------------------
__global__ __launch_bounds__(512, 2) void gemm_i8_kernel(
    const unsigned char* __restrict__ a8, const unsigned char* __restrict__ w8,
    const float* __restrict__ a_scale, const float* __restrict__ w_scale,
    float* __restrict__ out) {

    __shared__ __attribute__((aligned(16))) unsigned char sm[3][2][TILE_BYTES]; // 96 KB

    const int t = threadIdx.x;
    const int lane = t & 63;
    const int wid = t >> 6;           // 0..7
    const int wr = wid >> 2;          // 0..1 : rows [wr*128, +128)
    const int wc = wid & 3;           // 0..3 : cols [wc*64, +64)
    const int hi = lane >> 5;         // k-half within 32-k chunk
    const int lo32 = lane & 31;

    // XCD-aware swizzle: grid 512, 512 % 8 == 0 -> bijective chunked map
    int bid = blockIdx.x;
    bid = (bid & 7) * (512 / 8) + (bid >> 3);
    const int mt = bid >> 4;          // 0..31
    const int nt = bid & 15;          // 0..15

    const unsigned char* a_tiles = a8 + (size_t)mt * NT_K * TILE_BYTES;
    const unsigned char* w_tiles = w8 + (size_t)nt * NT_K * TILE_BYTES;

    v16i acc[4][2] = {};

#define STAGE_TILE(b2, gaP, gbP) do {                                             \
    __builtin_amdgcn_global_load_lds((gas1_t)((gaP) + t * 16),                    \
        (las3_t)&sm[b2][0][t * 16], 16, 0, 0);                                    \
    __builtin_amdgcn_global_load_lds((gas1_t)((gaP) + 8192 + t * 16),             \
        (las3_t)&sm[b2][0][8192 + t * 16], 16, 0, 0);                             \
    __builtin_amdgcn_global_load_lds((gas1_t)((gbP) + t * 16),                    \
        (las3_t)&sm[b2][1][t * 16], 16, 0, 0);                                    \
    __builtin_amdgcn_global_load_lds((gas1_t)((gbP) + 8192 + t * 16),             \
        (las3_t)&sm[b2][1][8192 + t * 16], 16, 0, 0);                             \
} while (0)

#define ITER(b0, b2, Tcur) do {                                                   \
    const int Tp = ((Tcur) + 2 <= NT_K - 1) ? (Tcur) + 2 : NT_K - 1;              \
    STAGE_TILE(b2, a_tiles + (size_t)Tp * TILE_BYTES,                             \
                   w_tiles + (size_t)Tp * TILE_BYTES);                            \
    v4i af[2][4], bf[2][2];                                                       \
    const unsigned char* lA = &sm[b0][0][0];                                      \
    const unsigned char* lB = &sm[b0][1][0];                                      \
    _Pragma("unroll")                                                             \
    for (int kc = 0; kc < 2; ++kc) {                                              \
        const int so = (kc * 2 + hi) * 4096;                                      \
        _Pragma("unroll")                                                         \
        for (int mi = 0; mi < 4; ++mi)                                            \
            af[kc][mi] = *(const v4i*)(lA + so + (wr * 128 + mi * 32 + lo32) * 16);\
        _Pragma("unroll")                                                         \
        for (int ni = 0; ni < 2; ++ni)                                            \
            bf[kc][ni] = *(const v4i*)(lB + so + (wc * 64 + ni * 32 + lo32) * 16);\
    }                                                                             \
    asm volatile("s_waitcnt vmcnt(4)" ::: "memory");                              \
    __builtin_amdgcn_s_barrier();                                                 \
    asm volatile("s_waitcnt lgkmcnt(0)" ::: "memory");                            \
    __builtin_amdgcn_sched_barrier(0);                                            \
    __builtin_amdgcn_s_setprio(1);                                                \
    _Pragma("unroll")                                                             \
    for (int kc = 0; kc < 2; ++kc)                                                \
        _Pragma("unroll")                                                         \
        for (int mi = 0; mi < 4; ++mi)                                            \
            _Pragma("unroll")                                                     \
            for (int ni = 0; ni < 2; ++ni)                                        \
                acc[mi][ni] = __builtin_amdgcn_mfma_i32_32x32x32_i8(              \
                    af[kc][mi], bf[kc][ni], acc[mi][ni], 0, 0, 0);                \
    __builtin_amdgcn_s_setprio(0);                                                \
    __builtin_amdgcn_s_barrier();                                                 \
} while (0)

    // Prologue: stage tiles 0 and 1; vmcnt(4) -> tile 0 landed.
    STAGE_TILE(0, a_tiles, w_tiles);
    STAGE_TILE(1, a_tiles + TILE_BYTES, w_tiles + TILE_BYTES);
    asm volatile("s_waitcnt vmcnt(4)" ::: "memory");
    __builtin_amdgcn_s_barrier();

    // 64 K-tiles = 21 x (3 unrolled iters) + 1 final.
    int T = 0;
#pragma unroll 1
    for (int u = 0; u < 21; ++u) {
        ITER(0, 2, T);
        ITER(1, 0, T + 1);
        ITER(2, 1, T + 2);
        T += 3;
    }
    ITER(0, 2, 63);   // reads buf0 (tile 63 staged at iter 61); dup-stage to buf2

    asm volatile("s_waitcnt vmcnt(0)" ::: "memory");  // drain before exit

#undef STAGE_TILE
#undef ITER

    // Epilogue: dequant + store f32 (rows of 32 consecutive floats per lane-group).
    const int row0 = mt * 256 + wr * 128;
    const int col0 = nt * 256 + wc * 64;
#pragma unroll
    for (int mi = 0; mi < 4; ++mi) {
#pragma unroll
        for (int r = 0; r < 16; ++r) {
            const int row = row0 + mi * 32 + (r & 3) + 8 * (r >> 2) + 4 * hi;
            const float as = a_scale[row];
            float* orow = out + (size_t)row * N_TOT + col0 + lo32;
#pragma unroll
            for (int ni = 0; ni < 2; ++ni)
                orow[ni * 32] = (float)acc[mi][ni][r] * as * w_scale[col0 + ni * 32 + lo32];
        }
    }
}

// ---------------------------------------------------------------------------
extern "C" void kernel_launch(void* const* d_in, const int* in_sizes, int n_in,
                              void* d_out, int out_size, void* d_ws, size_t ws_size,
                              hipStream_t stream) {
    const int*   a       = (const int*)d_in[0];
    const float* a_scale = (const float*)d_in[1];
    const int*   w       = (const int*)d_in[2];
    const float* w_scale = (const float*)d_in[3];
    float*       out     = (float*)d_out;

    // Workspace: a8 (32 MB) + w8 (16 MB) = 48 MB
    unsigned char* a8 = (unsigned char*)d_ws;
    unsigned char* w8 = a8 + (size_t)M_TOT * K_TOT;

    pack_a_kernel<<<(M_TOT / 256) * NT_K, 256, 0, stream>>>(a, a8);   // 2048 blocks
    pack_w_kernel<<<(N_TOT / 256) * NT_K, 256, 0, stream>>>(w, w8);   // 1024 blocks
    gemm_i8_kernel<<<(M_TOT / 256) * (N_TOT / 256), 512, 0, stream>>>(
        a8, w8, a_scale, w_scale, out);                               // 512 blocks
}

// Round 5
// 396.986 us; speedup vs baseline: 1.0644x; 1.0133x over previous
//
#include <hip/hip_runtime.h>

// out[M,N] = (int8 a[M,K] @ int8 w[K,N]) * a_scale[M] * w_scale[N]
// M = 8192, K = 4096, N = 4096. Inputs arrive as int32 containers.
//
// R4 measured: total 402; GEMM 143 (MfmaUtil 42.6, conflicts 0); R3(2-phase)
// == R4(1-phase) => phase granularity not binding. R5: (1) prefetch depth 3
// (4 LDS buffers, vmcnt(8)); (2) kc-split lgkmcnt(6)/(0) so kc1's LDS reads
// are served under kc0's MFMA cluster; (3) epilogue scales via LDS broadcast;
// (4) packs shrunk to 32 KB LDS for ~5 blocks/CU occupancy.

#define M_TOT 8192
#define N_TOT 4096
#define K_TOT 4096
#define NT_K  (K_TOT / 64)     // 64 K-tiles of depth 64
#define TILE_BYTES 16384       // 256 rows x 64 k x 1 B

typedef int v4i  __attribute__((ext_vector_type(4)));
typedef int v16i __attribute__((ext_vector_type(16)));

typedef const __attribute__((address_space(1))) unsigned char* gas1_t;
typedef __attribute__((address_space(3))) unsigned char* las3_t;

__device__ __forceinline__ int pack4(int4 v) {
    return (int)((unsigned)(v.x & 255) | ((unsigned)(v.y & 255) << 8) |
                 ((unsigned)(v.z & 255) << 16) | ((unsigned)v.w << 24));
}

// ---------------------------------------------------------------------------
// Pack A: a[M][K] int32 -> a8 tiles [mt(32)][kt(64)][slot(4)][m(256)][16B]
// Block = 128-row half-tile (32 KB LDS -> ~5 blocks/CU).
// Phase 1: coalesced int4 reads (16 lanes cover one row's 256 B) -> LDS,
//   XOR-swizzled 16B chunks. Phase 2: gather 4 swizzled chunks of one row's
//   slot, pack to 16 B, coalesced store.
// ---------------------------------------------------------------------------
__global__ __launch_bounds__(256) void pack_a_kernel(const int* __restrict__ a,
                                                     unsigned char* __restrict__ a8) {
    __shared__ int4 stage[128 * 16];        // 32 KB, addr16 = r*16 + (c ^ (r&15))
    const int b = blockIdx.x;               // m128_idx*64 + kt
    const int kt = b & (NT_K - 1);
    const int m128 = b >> 6;                // 0..63
    const int mt = m128 >> 1;
    const int mhalf = m128 & 1;
    const int t = threadIdx.x;
#pragma unroll
    for (int i = 0; i < 8; ++i) {
        const int idx16 = i * 256 + t;
        const int r = idx16 >> 4;           // row 0..127
        const int c = idx16 & 15;           // 16B chunk within row
        int4 v = *(const int4*)(a + (size_t)(mt * 256 + mhalf * 128 + r) * K_TOT +
                                kt * 64 + c * 4);
        stage[r * 16 + (c ^ (r & 15))] = v;
    }
    __syncthreads();
    unsigned char* outp = a8 + (size_t)(mt * NT_K + kt) * TILE_BYTES;
#pragma unroll
    for (int q = 0; q < 2; ++q) {
        const int id = q * 256 + t;         // 0..511
        const int j = id >> 7;              // slot 0..3
        const int r = id & 127;             // row 0..127
        int4 d0 = stage[r * 16 + ((j * 4 + 0) ^ (r & 15))];
        int4 d1 = stage[r * 16 + ((j * 4 + 1) ^ (r & 15))];
        int4 d2 = stage[r * 16 + ((j * 4 + 2) ^ (r & 15))];
        int4 d3 = stage[r * 16 + ((j * 4 + 3) ^ (r & 15))];
        int4 p = { pack4(d0), pack4(d1), pack4(d2), pack4(d3) };
        *(int4*)(outp + j * 4096 + (mhalf * 128 + r) * 16) = p;
    }
}

// ---------------------------------------------------------------------------
// Pack W (transpose): w[K][N] int32 -> w8 tiles [nt(16)][kt(64)][slot(4)][n(256)][16B]
// Block = 128-col half-tile (32 KB LDS). Phase 1: coalesced reads -> LDS [k][n].
// Phase 2: column gather (stride 128 dwords -> banks spread), pack, store.
// ---------------------------------------------------------------------------
__global__ __launch_bounds__(256) void pack_w_kernel(const int* __restrict__ w,
                                                     unsigned char* __restrict__ w8) {
    __shared__ int stage[64 * 128];         // 32 KB, [k][n] dwords
    const int b = blockIdx.x;               // n128_idx*64 + kt
    const int kt = b & (NT_K - 1);
    const int n128 = b >> 6;                // 0..31
    const int nt = n128 >> 1;
    const int nhalf = n128 & 1;
    const int t = threadIdx.x;
#pragma unroll
    for (int i = 0; i < 8; ++i) {
        const int idx = i * 256 + t;        // 0..2047
        const int k = idx >> 5;             // k-row 0..63
        const int c4 = idx & 31;            // int4 chunk (32 per row)
        int4 v = *(const int4*)(w + (size_t)(kt * 64 + k) * N_TOT +
                                nt * 256 + nhalf * 128 + c4 * 4);
        *(int4*)&stage[k * 128 + c4 * 4] = v;
    }
    __syncthreads();
    unsigned char* outp = w8 + (size_t)(nt * NT_K + kt) * TILE_BYTES;
#pragma unroll
    for (int q = 0; q < 2; ++q) {
        const int id = q * 256 + t;         // 0..511
        const int j = id >> 7;              // slot 0..3
        const int n = id & 127;             // col 0..127
        int4 p;
#pragma unroll
        for (int qq = 0; qq < 4; ++qq) {
            int4 bb;
            bb.x = stage[(j * 16 + qq * 4 + 0) * 128 + n];
            bb.y = stage[(j * 16 + qq * 4 + 1) * 128 + n];
            bb.z = stage[(j * 16 + qq * 4 + 2) * 128 + n];
            bb.w = stage[(j * 16 + qq * 4 + 3) * 128 + n];
            ((int*)&p)[qq] = pack4(bb);
        }
        *(int4*)(outp + j * 4096 + (nhalf * 128 + n) * 16) = p;
    }
}

// ---------------------------------------------------------------------------
// GEMM: 256x256 tile, BK=64, 8 waves (2M x 4N; 128x64 out per wave),
// mfma_i32_32x32x32_i8, QUAD-buffered LDS (128 KB), prefetch distance 3.
// Per K-tile: { stage tile T+3 -> buf (T+3)%4 (4 x global_load_lds 16B);
//   12 x ds_read_b128 ordered {af0,bf0 | af1,bf1}; vmcnt(8) [allows T+3,T+2
//   in flight; forces T+1 landed]; barrier; lgkmcnt(6) -> 8 MFMA kc0;
//   lgkmcnt(0) -> 8 MFMA kc1; barrier }. vmcnt never 0 in-loop (T4).
// Tile T's own loads were forced complete by iter T-1's vmcnt(8).
//
// A-frag: lane l holds A[row = l&31][k = kc*32 + (l>>5)*16 + j], j=0..15
// B-frag: lane l holds B[k][col = l&31] (consistent k-permutation cancels)
// D: lane l, reg r -> row = (r&3) + 8*(r>>2) + 4*(l>>5), col = l&31
// ---------------------------------------------------------------------------
__global__ __launch_bounds__(512, 2) void gemm_i8_kernel(
    const unsigned char* __restrict__ a8, const unsigned char* __restrict__ w8,
    const float* __restrict__ a_scale, const float* __restrict__ w_scale,
    float* __restrict__ out) {

    __shared__ __attribute__((aligned(16))) unsigned char sm[4][2][TILE_BYTES]; // 128 KB

    const int t = threadIdx.x;
    const int lane = t & 63;
    const int wid = t >> 6;           // 0..7
    const int wr = wid >> 2;          // 0..1 : rows [wr*128, +128)
    const int wc = wid & 3;           // 0..3 : cols [wc*64, +64)
    const int hi = lane >> 5;         // k-half within 32-k chunk
    const int lo32 = lane & 31;

    // XCD-aware swizzle: grid 512, 512 % 8 == 0 -> bijective chunked map
    int bid = blockIdx.x;
    bid = (bid & 7) * (512 / 8) + (bid >> 3);
    const int mt = bid >> 4;          // 0..31
    const int nt = bid & 15;          // 0..15

    const unsigned char* a_tiles = a8 + (size_t)mt * NT_K * TILE_BYTES;
    const unsigned char* w_tiles = w8 + (size_t)nt * NT_K * TILE_BYTES;

    v16i acc[4][2] = {};

#define STAGE_TILE(bN, gaP, gbP) do {                                             \
    __builtin_amdgcn_global_load_lds((gas1_t)((gaP) + t * 16),                    \
        (las3_t)&sm[bN][0][t * 16], 16, 0, 0);                                    \
    __builtin_amdgcn_global_load_lds((gas1_t)((gaP) + 8192 + t * 16),             \
        (las3_t)&sm[bN][0][8192 + t * 16], 16, 0, 0);                             \
    __builtin_amdgcn_global_load_lds((gas1_t)((gbP) + t * 16),                    \
        (las3_t)&sm[bN][1][t * 16], 16, 0, 0);                                    \
    __builtin_amdgcn_global_load_lds((gas1_t)((gbP) + 8192 + t * 16),             \
        (las3_t)&sm[bN][1][8192 + t * 16], 16, 0, 0);                             \
} while (0)

#define ITER(b0, b3, Tcur) do {                                                   \
    const int Tp = ((Tcur) + 3 <= NT_K - 1) ? (Tcur) + 3 : NT_K - 1;              \
    STAGE_TILE(b3, a_tiles + (size_t)Tp * TILE_BYTES,                             \
                   w_tiles + (size_t)Tp * TILE_BYTES);                            \
    const unsigned char* lA = &sm[b0][0][0];                                      \
    const unsigned char* lB = &sm[b0][1][0];                                      \
    v4i af0[4], bf0[2], af1[4], bf1[2];                                           \
    _Pragma("unroll")                                                             \
    for (int mi = 0; mi < 4; ++mi)                                                \
        af0[mi] = *(const v4i*)(lA + hi * 4096 + (wr * 128 + mi * 32 + lo32) * 16);\
    _Pragma("unroll")                                                             \
    for (int ni = 0; ni < 2; ++ni)                                                \
        bf0[ni] = *(const v4i*)(lB + hi * 4096 + (wc * 64 + ni * 32 + lo32) * 16);\
    __builtin_amdgcn_sched_barrier(0); /* keep kc0 reads oldest in lgkm queue */  \
    _Pragma("unroll")                                                             \
    for (int mi = 0; mi < 4; ++mi)                                                \
        af1[mi] = *(const v4i*)(lA + (2 + hi) * 4096 + (wr * 128 + mi * 32 + lo32) * 16);\
    _Pragma("unroll")                                                             \
    for (int ni = 0; ni < 2; ++ni)                                                \
        bf1[ni] = *(const v4i*)(lB + (2 + hi) * 4096 + (wc * 64 + ni * 32 + lo32) * 16);\
    asm volatile("s_waitcnt vmcnt(8)" ::: "memory");                              \
    __builtin_amdgcn_s_barrier();                                                 \
    asm volatile("s_waitcnt lgkmcnt(6)" ::: "memory");                            \
    __builtin_amdgcn_sched_barrier(0);                                            \
    __builtin_amdgcn_s_setprio(1);                                                \
    _Pragma("unroll")                                                             \
    for (int mi = 0; mi < 4; ++mi)                                                \
        _Pragma("unroll")                                                         \
        for (int ni = 0; ni < 2; ++ni)                                            \
            acc[mi][ni] = __builtin_amdgcn_mfma_i32_32x32x32_i8(                  \
                af0[mi], bf0[ni], acc[mi][ni], 0, 0, 0);                          \
    asm volatile("s_waitcnt lgkmcnt(0)" ::: "memory");                            \
    __builtin_amdgcn_sched_barrier(0);                                            \
    _Pragma("unroll")                                                             \
    for (int mi = 0; mi < 4; ++mi)                                                \
        _Pragma("unroll")                                                         \
        for (int ni = 0; ni < 2; ++ni)                                            \
            acc[mi][ni] = __builtin_amdgcn_mfma_i32_32x32x32_i8(                  \
                af1[mi], bf1[ni], acc[mi][ni], 0, 0, 0);                          \
    __builtin_amdgcn_s_setprio(0);                                                \
    __builtin_amdgcn_s_barrier();                                                 \
} while (0)

    // Prologue: stage tiles 0,1,2 into bufs 0,1,2; vmcnt(8) -> tile 0 landed.
    STAGE_TILE(0, a_tiles, w_tiles);
    STAGE_TILE(1, a_tiles + TILE_BYTES, w_tiles + TILE_BYTES);
    STAGE_TILE(2, a_tiles + 2 * TILE_BYTES, w_tiles + 2 * TILE_BYTES);
    asm volatile("s_waitcnt vmcnt(8)" ::: "memory");
    __builtin_amdgcn_s_barrier();

    // 64 K-tiles = 16 x (4 unrolled iters). Buffer indices constant-fold.
    int T = 0;
#pragma unroll 1
    for (int u = 0; u < 16; ++u) {
        ITER(0, 3, T);
        ITER(1, 0, T + 1);
        ITER(2, 1, T + 2);
        ITER(3, 2, T + 3);
        T += 4;
    }

    asm volatile("s_waitcnt vmcnt(0)" ::: "memory");  // drain before LDS reuse

#undef STAGE_TILE
#undef ITER

    // Stash scales in LDS (reuse sm), broadcast-read in epilogue.
    __syncthreads();
    float* scA = (float*)&sm[0][0][0];      // 256 floats
    float* scW = scA + 256;                 // 256 floats
    if (t < 256) scA[t] = a_scale[mt * 256 + t];
    else         scW[t - 256] = w_scale[nt * 256 + (t - 256)];
    __syncthreads();

    // Epilogue: dequant + store f32.
    const int row0 = mt * 256 + wr * 128;
    const int col0 = nt * 256 + wc * 64;
#pragma unroll
    for (int mi = 0; mi < 4; ++mi) {
#pragma unroll
        for (int r = 0; r < 16; ++r) {
            const int rloc = wr * 128 + mi * 32 + (r & 3) + 8 * (r >> 2) + 4 * hi;
            const float as = scA[rloc];
            float* orow = out + (size_t)(row0 - wr * 128 + rloc) * N_TOT + col0 + lo32;
#pragma unroll
            for (int ni = 0; ni < 2; ++ni)
                orow[ni * 32] = (float)acc[mi][ni][r] * as * scW[wc * 64 + ni * 32 + lo32];
        }
    }
    (void)row0;
}

// ---------------------------------------------------------------------------
extern "C" void kernel_launch(void* const* d_in, const int* in_sizes, int n_in,
                              void* d_out, int out_size, void* d_ws, size_t ws_size,
                              hipStream_t stream) {
    const int*   a       = (const int*)d_in[0];
    const float* a_scale = (const float*)d_in[1];
    const int*   w       = (const int*)d_in[2];
    const float* w_scale = (const float*)d_in[3];
    float*       out     = (float*)d_out;

    // Workspace: a8 (32 MB) + w8 (16 MB) = 48 MB
    unsigned char* a8 = (unsigned char*)d_ws;
    unsigned char* w8 = a8 + (size_t)M_TOT * K_TOT;

    pack_a_kernel<<<(M_TOT / 128) * NT_K, 256, 0, stream>>>(a, a8);   // 4096 blocks
    pack_w_kernel<<<(N_TOT / 128) * NT_K, 256, 0, stream>>>(w, w8);   // 2048 blocks
    gemm_i8_kernel<<<(M_TOT / 256) * (N_TOT / 256), 512, 0, stream>>>(
        a8, w8, a_scale, w_scale, out);                               // 512 blocks
}